// Round 22
// baseline (58.807 us; speedup 1.0000x reference)
//
#include <hip/hip_runtime.h>
#include <hip/hip_bf16.h>

// ROUND 22: r21 base + u16-compressed dst planes. k12 packs dst->u16 (bit-exact,
// ids<20000); k3/k4 scan u16 planes: half the bytes AND half the load count
// (8 dsts per 16B load) — attacks the L3 miss-throughput limit of in-chain scans.

#define NN 20000
#define EE 320000
#define E4 (EE/4)
#define E8 (EE/8)       // u16-octet groups per plane
#define KK 4
#define FIN 512
#define FHID 256
#define FOUT 128
#define FHD 256
#define NH (2*FOUT+3)   // 259
#define CAP1 1024
#define MS2 128
#define BCAP 256
#define BMW 640

__device__ __forceinline__ float dinvf(int indeg) {
  // reference deg includes the self-loop -> always >= 1
  return rsqrtf((float)(indeg + 1));
}

__global__ __launch_bounds__(256) void kz_zero(int4* __restrict__ p, int n4) {
  int i = blockIdx.x * 256 + threadIdx.x;
  if (i < n4) p[i] = make_int4(0, 0, 0, 0);
}

// K12: scan dst planes; pack dst->u16 planes; collect L1 edges; CAS-claim slots.
__global__ __launch_bounds__(256) void k12_scan_claim(const int* __restrict__ ei,
                                                      const int* __restrict__ idx,
                                                      int* __restrict__ cnt1,
                                                      int* __restrict__ L1src,
                                                      int* __restrict__ L1sel,
                                                      int* __restrict__ reg,
                                                      int* __restrict__ slotNode,
                                                      int* __restrict__ mslots,
                                                      unsigned* __restrict__ bA,
                                                      unsigned short* __restrict__ d16) {
  int k = blockIdx.y;
  int* rk = reg + (size_t)k * NN;
  unsigned* bAk = bA + k * BMW;
  int t0 = idx[2 * k], t1 = idx[2 * k + 1];
  if (blockIdx.x == 0 && threadIdx.x < 2) {
    int node = (threadIdx.x == 0) ? t0 : t1;
    if (atomicCAS(&rk[node], 0, -2) == 0) {
      int s = atomicAdd(&mslots[k], 1);
      if (s < MS2) {
        slotNode[k * MS2 + s] = node; rk[node] = s + 1;
        atomicOr(&bAk[node >> 5], 1u << (node & 31));
      }
    }
  }
  int e4 = blockIdx.x * blockDim.x + threadIdx.x;
  if (e4 >= E4) return;
  const int* srcp = ei + (size_t)k * 2 * EE;
  int4 d4 = ((const int4*)(srcp + EE))[e4];
  // pack 4 dsts into u16x4 (8B coalesced store)
  {
    uint2 pk;
    pk.x = (unsigned)(d4.x & 0xFFFF) | ((unsigned)(d4.y & 0xFFFF) << 16);
    pk.y = (unsigned)(d4.z & 0xFFFF) | ((unsigned)(d4.w & 0xFFFF) << 16);
    ((uint2*)(d16 + (size_t)k * EE))[e4] = pk;
  }
  int ds[4] = {d4.x, d4.y, d4.z, d4.w};
  #pragma unroll
  for (int c = 0; c < 4; c++) {
    bool h0 = (ds[c] == t0), h1 = (ds[c] == t1);
    if (h0 || h1) {
      int u = srcp[e4 * 4 + c];
      if (h0) {
        int p = atomicAdd(&cnt1[k], 1);
        if (p < CAP1) { L1src[k * CAP1 + p] = u; L1sel[k * CAP1 + p] = 0; }
      }
      if (h1) {
        int p = atomicAdd(&cnt1[k], 1);
        if (p < CAP1) { L1src[k * CAP1 + p] = u; L1sel[k * CAP1 + p] = 1; }
      }
      if (atomicCAS(&rk[u], 0, -2) == 0) {
        int s = atomicAdd(&mslots[k], 1);
        if (s < MS2) {
          slotNode[k * MS2 + s] = u; rk[u] = s + 1;
          atomicOr(&bAk[u >> 5], 1u << (u & 31));
        }
      }
    }
  }
}

// K3: scan u16 dst plane (8 dsts / 16B load) with LDS slot-bitmap test.
__global__ __launch_bounds__(256) void k3_scanL2(const int* __restrict__ ei,
                                                 const unsigned short* __restrict__ d16,
                                                 const int* __restrict__ reg,
                                                 const unsigned* __restrict__ bA,
                                                 unsigned* __restrict__ bB,
                                                 int* __restrict__ bcnt,
                                                 int* __restrict__ bucket) {
  __shared__ unsigned lbA[BMW];   // 2.5 KB
  int k = blockIdx.y;
  const unsigned* bAk = bA + k * BMW;
  for (int i = threadIdx.x; i < BMW; i += 256) lbA[i] = bAk[i];
  __syncthreads();
  int g8 = blockIdx.x * blockDim.x + threadIdx.x;
  if (g8 >= E8) return;
  uint4 q = ((const uint4*)(d16 + (size_t)k * EE))[g8];
  const int* srcp = ei + (size_t)k * 2 * EE;
  const int* rk = reg + (size_t)k * NN;
  unsigned* bBk = bB + k * BMW;
  unsigned w[4] = {q.x, q.y, q.z, q.w};
  #pragma unroll
  for (int c = 0; c < 8; c++) {
    int d = (int)((w[c >> 1] >> ((c & 1) * 16)) & 0xFFFFu);
    if ((lbA[d >> 5] >> (d & 31)) & 1u) {
      int s = rk[d] - 1;
      int u = srcp[g8 * 8 + c];
      int p = atomicAdd(&bcnt[k * MS2 + s], 1);
      if (p < BCAP) bucket[((size_t)k * MS2 + s) * BCAP + p] = u;
      atomicOr(&bBk[u >> 5], 1u << (u & 31));
    }
  }
}

// K4: scan u16 dst plane with LDS deg-needed-bitmap test; sparse atomicAdd.
__global__ __launch_bounds__(256) void k4_deg(const unsigned short* __restrict__ d16,
                                              const unsigned* __restrict__ bB,
                                              int* __restrict__ deg) {
  __shared__ unsigned lbB[BMW];
  int k = blockIdx.y;
  const unsigned* bBk = bB + k * BMW;
  for (int i = threadIdx.x; i < BMW; i += 256) lbB[i] = bBk[i];
  __syncthreads();
  int g8 = blockIdx.x * blockDim.x + threadIdx.x;
  if (g8 >= E8) return;
  uint4 q = ((const uint4*)(d16 + (size_t)k * EE))[g8];
  unsigned w[4] = {q.x, q.y, q.z, q.w};
  #pragma unroll
  for (int c = 0; c < 8; c++) {
    int d = (int)((w[c >> 1] >> ((c & 1) * 16)) & 0xFFFFu);
    if ((lbB[d >> 5] >> (d & 31)) & 1u) atomicAdd(&deg[k * NN + d], 1);
  }
}

// K5: r15 body (8-way float4 gather + LDS reduce + GEMV1 + relu + GEMV2).
__global__ __launch_bounds__(1024) void k5_slotmlp(const int* __restrict__ slotNode,
                                                   const int* __restrict__ mslots,
                                                   const int* __restrict__ bcnt,
                                                   const int* __restrict__ bucket,
                                                   const int* __restrict__ deg,
                                                   const float* __restrict__ x,
                                                   const float* __restrict__ W1,
                                                   const float* __restrict__ b1,
                                                   const float* __restrict__ W2,
                                                   float* __restrict__ HW2) {
  __shared__ float partg[8][FIN];
  __shared__ float aggS[FIN];
  __shared__ float part[4][FHID];
  __shared__ float hrow[FHID];
  __shared__ float part2[8][FOUT];
  __shared__ int   uS[BCAP];
  __shared__ float duS[BCAP];
  int k = blockIdx.y, s = blockIdx.x;
  if (s >= mslots[k]) return;
  int tid = threadIdx.x;
  int node = slotNode[k * MS2 + s];
  int rawbc = bcnt[k * MS2 + s];
  int nb = min(rawbc, BCAP);
  const int* bk = bucket + ((size_t)k * MS2 + s) * BCAP;
  if (tid < nb) {
    int u = bk[tid];
    uS[tid] = u;
    duS[tid] = dinvf(deg[k * NN + u]);
  }
  __syncthreads();
  float dn = dinvf(rawbc);   // slot in-degree == bucket count (validated r13+)
  int g = tid >> 7, f4 = tid & 127;
  float ax = 0.f, ay = 0.f, az = 0.f, aw = 0.f;
  if (g == 0) {
    float4 v = ((const float4*)(x + (size_t)node * FIN))[f4];
    ax = dn * v.x; ay = dn * v.y; az = dn * v.z; aw = dn * v.w;
  }
  for (int e = g; e < nb; e += 8) {
    float du = duS[e];
    float4 v = ((const float4*)(x + (size_t)uS[e] * FIN))[f4];
    ax += du * v.x; ay += du * v.y; az += du * v.z; aw += du * v.w;
  }
  { float* pw = &partg[g][f4 * 4]; pw[0] = ax; pw[1] = ay; pw[2] = az; pw[3] = aw; }
  __syncthreads();
  if (tid < FIN) {
    float ssum = 0.f;
    #pragma unroll
    for (int g2 = 0; g2 < 8; g2++) ssum += partg[g2][tid];
    aggS[tid] = dn * ssum;
  }
  __syncthreads();
  {
    int q = tid >> 8, j = tid & (FHID - 1);
    float acc = 0.f;
    const float* w1p = W1 + (size_t)(q * 128) * FHID + j;
    const float* ap = aggS + q * 128;
    #pragma unroll 8
    for (int kk = 0; kk < 128; kk++) acc += ap[kk] * w1p[(size_t)kk * FHID];
    part[q][j] = acc;
  }
  __syncthreads();
  if (tid < FHID) {
    float v = part[0][tid] + part[1][tid] + part[2][tid] + part[3][tid] + b1[tid];
    hrow[tid] = v > 0.f ? v : 0.f;
  }
  __syncthreads();
  {
    int p = tid >> 7, j = tid & (FOUT - 1);
    float a2 = 0.f;
    const float* w2p = W2 + (size_t)(p * 32) * FOUT + j;
    const float* hp = hrow + p * 32;
    #pragma unroll 8
    for (int kk = 0; kk < 32; kk++) a2 += hp[kk] * w2p[(size_t)kk * FOUT];
    part2[p][j] = a2;
  }
  __syncthreads();
  if (tid < FOUT) {
    float sv = part2[0][tid] + part2[1][tid] + part2[2][tid] + part2[3][tid] +
               part2[4][tid] + part2[5][tid] + part2[6][tid] + part2[7][tid];
    HW2[((size_t)k * MS2 + s) * FOUT + tid] = sv;
  }
}

// K6: parallel resolve (r21) + accumulate + decoder.
__global__ __launch_bounds__(256) void k6_decode(const float* __restrict__ HW2,
                                                 const float* __restrict__ b2,
                                                 const int* __restrict__ cnt1,
                                                 const int* __restrict__ L1src,
                                                 const int* __restrict__ L1sel,
                                                 const int* __restrict__ idx,
                                                 const int* __restrict__ reg,
                                                 const int* __restrict__ bcnt,
                                                 const float* __restrict__ value,
                                                 const float* __restrict__ Wd,
                                                 const float* __restrict__ bd,
                                                 const float* __restrict__ Wp,
                                                 const float* __restrict__ bp,
                                                 float* __restrict__ out) {
  __shared__ float coefS[CAP1 + 2];
  __shared__ short slotS[CAP1 + 2];
  __shared__ short tselS[CAP1 + 2];
  __shared__ float hD[NH + 1];
  __shared__ float red[4];
  int k = blockIdx.x;
  int tid = threadIdx.x;
  const int* rk = reg + (size_t)k * NN;
  int n1 = min(cnt1[k], CAP1);
  int t0 = idx[2 * k], t1 = idx[2 * k + 1];
  int ts0 = rk[t0] - 1, ts1 = rk[t1] - 1;
  float dit0 = dinvf(bcnt[k * MS2 + ts0]);
  float dit1 = dinvf(bcnt[k * MS2 + ts1]);
  for (int i = tid; i < n1; i += 256) {
    int sn = L1src[k * CAP1 + i];
    int ts = L1sel[k * CAP1 + i];
    int ss = rk[sn] - 1;
    float dis = dinvf(bcnt[k * MS2 + ss]);
    coefS[i] = dis * (ts ? dit1 : dit0);
    slotS[i] = (short)ss;
    tselS[i] = (short)ts;
  }
  if (tid == 0) {
    coefS[n1] = dit0 * dit0; slotS[n1] = (short)ts0; tselS[n1] = 0;
    coefS[n1 + 1] = dit1 * dit1; slotS[n1 + 1] = (short)ts1; tselS[n1 + 1] = 1;
  }
  __syncthreads();
  {
    int tsel = tid >> 7, j = tid & 127;
    float acc = b2[j];
    int m = n1 + 2;
    for (int i = 0; i < m; i++) {
      if ((int)tselS[i] == tsel)
        acc += coefS[i] * HW2[((size_t)k * MS2 + (int)slotS[i]) * FOUT + j];
    }
    hD[tid] = acc;
    if (tid < 3) hD[2 * FOUT + tid] = value[k * 3 + tid];
  }
  __syncthreads();
  float a2 = bd[tid];
  for (int i = 0; i < NH; i++) a2 += hD[i] * Wd[(size_t)i * FHD + tid];
  float o = a2 > 0.f ? a2 : 0.f;
  float r = o * Wp[tid];
  for (int o2 = 32; o2 > 0; o2 >>= 1) r += __shfl_down(r, o2);
  if ((tid & 63) == 0) red[tid >> 6] = r;
  __syncthreads();
  if (tid == 0) {
    float ssum = red[0] + red[1] + red[2] + red[3] + bp[0];
    out[k] = 1.f / (1.f + expf(-ssum));
  }
}

extern "C" void kernel_launch(void* const* d_in, const int* in_sizes, int n_in,
                              void* d_out, int out_size, void* d_ws, size_t ws_size,
                              hipStream_t stream) {
  const float* x     = (const float*)d_in[0];
  const int*   ei    = (const int*)d_in[1];
  const float* value = (const float*)d_in[2];
  const int*   idx   = (const int*)d_in[3];
  const float* W1    = (const float*)d_in[4];
  const float* b1    = (const float*)d_in[5];
  const float* W2    = (const float*)d_in[6];
  const float* b2    = (const float*)d_in[7];
  const float* Wd    = (const float*)d_in[8];
  const float* bd    = (const float*)d_in[9];
  const float* Wp    = (const float*)d_in[10];
  const float* bp    = (const float*)d_in[11];
  float* out = (float*)d_out;

  char* ws = (char*)d_ws;
  size_t off = 0;
  auto alloc = [&](size_t bytes) -> void* {
    void* p = ws + off;
    off = (off + bytes + 255) & ~(size_t)255;
    return p;
  };
  // --- zeroed region (one kz_zero): reg, deg, bA, bB, bcnt, cnt1, mslots ---
  size_t zints = (size_t)(2 * KK * NN + 2 * KK * BMW + KK * MS2 + 2 * KK);
  int* reg   = (int*)alloc(zints * sizeof(int));
  int* deg   = reg + KK * NN;
  unsigned* bA = (unsigned*)(deg + KK * NN);
  unsigned* bB = bA + KK * BMW;
  int* bcnt  = (int*)(bB + KK * BMW);
  int* cnt1  = bcnt + KK * MS2;
  int* mslots = cnt1 + KK;
  size_t zbytes = zints * sizeof(int);
  // --- non-zeroed scratch ---
  int* L1src = (int*)alloc((size_t)KK * CAP1 * sizeof(int));
  int* L1sel = (int*)alloc((size_t)KK * CAP1 * sizeof(int));
  int* slotNode = (int*)alloc((size_t)KK * MS2 * sizeof(int));
  int* bucket = (int*)alloc((size_t)KK * MS2 * BCAP * sizeof(int));
  float* HW2 = (float*)alloc((size_t)KK * MS2 * FOUT * sizeof(float));
  unsigned short* d16 = (unsigned short*)alloc((size_t)KK * EE * sizeof(unsigned short)); // 2.56 MB
  (void)ws_size; (void)in_sizes; (void)n_in; (void)out_size;

  int n4 = (int)((zbytes + 15) / 16);
  dim3 escan((E4 + 255) / 256, KK);
  dim3 escan8((E8 + 255) / 256, KK);

  kz_zero<<<(n4 + 255) / 256, 256, 0, stream>>>((int4*)reg, n4);
  k12_scan_claim<<<escan, 256, 0, stream>>>(ei, idx, cnt1, L1src, L1sel,
                                            reg, slotNode, mslots, bA, d16);
  k3_scanL2<<<escan8, 256, 0, stream>>>(ei, d16, reg, bA, bB, bcnt, bucket);
  k4_deg<<<escan8, 256, 0, stream>>>(d16, bB, deg);
  k5_slotmlp<<<dim3(MS2, KK), 1024, 0, stream>>>(slotNode, mslots, bcnt, bucket, deg,
                                                 x, W1, b1, W2, HW2);
  k6_decode<<<dim3(KK), 256, 0, stream>>>(HW2, b2, cnt1, L1src, L1sel, idx, reg, bcnt,
                                          value, Wd, bd, Wp, bp, out);
}

// Round 23
// 56.712 us; speedup vs baseline: 1.0369x; 1.0369x over previous
//
#include <hip/hip_runtime.h>
#include <hip/hip_bf16.h>

// ROUND 23: restore best config (r21, 57.3µs) after r22's u16 regression.
// Only change vs r21: uint4-vectorized bitmap staging in k3/k4.
// Session constraint (measured): parts ≈33µs (amplification-verified floors),
// inter-phase serialization ≈20µs (fusion attempts catastrophically negative:
// r2 grid.sync, r6 per-block fences; phase count is algorithmically minimal),
// harness-fixed ≈7µs.

#define NN 20000
#define EE 320000
#define E4 (EE/4)
#define KK 4
#define FIN 512
#define FHID 256
#define FOUT 128
#define FHD 256
#define NH (2*FOUT+3)   // 259
#define CAP1 1024
#define MS2 128
#define BCAP 256
#define BMW 640

__device__ __forceinline__ float dinvf(int indeg) {
  // reference deg includes the self-loop -> always >= 1
  return rsqrtf((float)(indeg + 1));
}

__global__ __launch_bounds__(256) void kz_zero(int4* __restrict__ p, int n4) {
  int i = blockIdx.x * 256 + threadIdx.x;
  if (i < n4) p[i] = make_int4(0, 0, 0, 0);
}

// K12: scan dst planes; collect L1 edges, CAS-claim slot nodes, set slot bitmap.
__global__ __launch_bounds__(256) void k12_scan_claim(const int* __restrict__ ei,
                                                      const int* __restrict__ idx,
                                                      int* __restrict__ cnt1,
                                                      int* __restrict__ L1src,
                                                      int* __restrict__ L1sel,
                                                      int* __restrict__ reg,
                                                      int* __restrict__ slotNode,
                                                      int* __restrict__ mslots,
                                                      unsigned* __restrict__ bA) {
  int k = blockIdx.y;
  int* rk = reg + (size_t)k * NN;
  unsigned* bAk = bA + k * BMW;
  int t0 = idx[2 * k], t1 = idx[2 * k + 1];
  if (blockIdx.x == 0 && threadIdx.x < 2) {
    int node = (threadIdx.x == 0) ? t0 : t1;
    if (atomicCAS(&rk[node], 0, -2) == 0) {
      int s = atomicAdd(&mslots[k], 1);
      if (s < MS2) {
        slotNode[k * MS2 + s] = node; rk[node] = s + 1;
        atomicOr(&bAk[node >> 5], 1u << (node & 31));
      }
    }
  }
  int e4 = blockIdx.x * blockDim.x + threadIdx.x;
  if (e4 >= E4) return;
  const int* srcp = ei + (size_t)k * 2 * EE;
  int4 d4 = ((const int4*)(srcp + EE))[e4];
  int ds[4] = {d4.x, d4.y, d4.z, d4.w};
  #pragma unroll
  for (int c = 0; c < 4; c++) {
    bool h0 = (ds[c] == t0), h1 = (ds[c] == t1);
    if (h0 || h1) {
      int u = srcp[e4 * 4 + c];
      if (h0) {
        int p = atomicAdd(&cnt1[k], 1);
        if (p < CAP1) { L1src[k * CAP1 + p] = u; L1sel[k * CAP1 + p] = 0; }
      }
      if (h1) {
        int p = atomicAdd(&cnt1[k], 1);
        if (p < CAP1) { L1src[k * CAP1 + p] = u; L1sel[k * CAP1 + p] = 1; }
      }
      if (atomicCAS(&rk[u], 0, -2) == 0) {
        int s = atomicAdd(&mslots[k], 1);
        if (s < MS2) {
          slotNode[k * MS2 + s] = u; rk[u] = s + 1;
          atomicOr(&bAk[u >> 5], 1u << (u & 31));
        }
      }
    }
  }
}

// K3: scan with LDS slot-bitmap membership test; bucket append + bB mark.
__global__ __launch_bounds__(256) void k3_scanL2(const int* __restrict__ ei,
                                                 const int* __restrict__ reg,
                                                 const unsigned* __restrict__ bA,
                                                 unsigned* __restrict__ bB,
                                                 int* __restrict__ bcnt,
                                                 int* __restrict__ bucket) {
  __shared__ unsigned lbA[BMW];   // 2.5 KB
  int k = blockIdx.y;
  // vectorized staging: 160 lanes x uint4 = 640 words in one round
  if (threadIdx.x < BMW / 4)
    ((uint4*)lbA)[threadIdx.x] = ((const uint4*)(bA + k * BMW))[threadIdx.x];
  __syncthreads();
  int e4 = blockIdx.x * blockDim.x + threadIdx.x;
  if (e4 >= E4) return;
  const int* srcp = ei + (size_t)k * 2 * EE;
  int4 d4 = ((const int4*)(srcp + EE))[e4];
  const int* rk = reg + (size_t)k * NN;
  unsigned* bBk = bB + k * BMW;
  int ds[4] = {d4.x, d4.y, d4.z, d4.w};
  #pragma unroll
  for (int c = 0; c < 4; c++) {
    int d = ds[c];
    if ((lbA[d >> 5] >> (d & 31)) & 1u) {
      int s = rk[d] - 1;
      int u = srcp[e4 * 4 + c];
      int p = atomicAdd(&bcnt[k * MS2 + s], 1);
      if (p < BCAP) bucket[((size_t)k * MS2 + s) * BCAP + p] = u;
      atomicOr(&bBk[u >> 5], 1u << (u & 31));
    }
  }
}

// K4: scan with LDS deg-needed-bitmap test; sparse atomicAdd for hits only.
__global__ __launch_bounds__(256) void k4_deg(const int* __restrict__ ei,
                                              const unsigned* __restrict__ bB,
                                              int* __restrict__ deg) {
  __shared__ unsigned lbB[BMW];
  int k = blockIdx.y;
  if (threadIdx.x < BMW / 4)
    ((uint4*)lbB)[threadIdx.x] = ((const uint4*)(bB + k * BMW))[threadIdx.x];
  __syncthreads();
  int e4 = blockIdx.x * blockDim.x + threadIdx.x;
  if (e4 >= E4) return;
  const int4* dst4 = (const int4*)(ei + (size_t)k * 2 * EE + EE);
  int4 d4 = dst4[e4];
  int ds[4] = {d4.x, d4.y, d4.z, d4.w};
  #pragma unroll
  for (int c = 0; c < 4; c++) {
    int d = ds[c];
    if ((lbB[d >> 5] >> (d & 31)) & 1u) atomicAdd(&deg[k * NN + d], 1);
  }
}

// K5: r15 body (8-way float4 gather + LDS reduce + GEMV1 + relu + GEMV2).
__global__ __launch_bounds__(1024) void k5_slotmlp(const int* __restrict__ slotNode,
                                                   const int* __restrict__ mslots,
                                                   const int* __restrict__ bcnt,
                                                   const int* __restrict__ bucket,
                                                   const int* __restrict__ deg,
                                                   const float* __restrict__ x,
                                                   const float* __restrict__ W1,
                                                   const float* __restrict__ b1,
                                                   const float* __restrict__ W2,
                                                   float* __restrict__ HW2) {
  __shared__ float partg[8][FIN];
  __shared__ float aggS[FIN];
  __shared__ float part[4][FHID];
  __shared__ float hrow[FHID];
  __shared__ float part2[8][FOUT];
  __shared__ int   uS[BCAP];
  __shared__ float duS[BCAP];
  int k = blockIdx.y, s = blockIdx.x;
  if (s >= mslots[k]) return;
  int tid = threadIdx.x;
  int node = slotNode[k * MS2 + s];
  int rawbc = bcnt[k * MS2 + s];
  int nb = min(rawbc, BCAP);
  const int* bk = bucket + ((size_t)k * MS2 + s) * BCAP;
  if (tid < nb) {
    int u = bk[tid];
    uS[tid] = u;
    duS[tid] = dinvf(deg[k * NN + u]);
  }
  __syncthreads();
  float dn = dinvf(rawbc);   // slot in-degree == bucket count (validated r13+)
  int g = tid >> 7, f4 = tid & 127;
  float ax = 0.f, ay = 0.f, az = 0.f, aw = 0.f;
  if (g == 0) {
    float4 v = ((const float4*)(x + (size_t)node * FIN))[f4];
    ax = dn * v.x; ay = dn * v.y; az = dn * v.z; aw = dn * v.w;
  }
  for (int e = g; e < nb; e += 8) {
    float du = duS[e];
    float4 v = ((const float4*)(x + (size_t)uS[e] * FIN))[f4];
    ax += du * v.x; ay += du * v.y; az += du * v.z; aw += du * v.w;
  }
  { float* pw = &partg[g][f4 * 4]; pw[0] = ax; pw[1] = ay; pw[2] = az; pw[3] = aw; }
  __syncthreads();
  if (tid < FIN) {
    float ssum = 0.f;
    #pragma unroll
    for (int g2 = 0; g2 < 8; g2++) ssum += partg[g2][tid];
    aggS[tid] = dn * ssum;
  }
  __syncthreads();
  {
    int q = tid >> 8, j = tid & (FHID - 1);
    float acc = 0.f;
    const float* w1p = W1 + (size_t)(q * 128) * FHID + j;
    const float* ap = aggS + q * 128;
    #pragma unroll 8
    for (int kk = 0; kk < 128; kk++) acc += ap[kk] * w1p[(size_t)kk * FHID];
    part[q][j] = acc;
  }
  __syncthreads();
  if (tid < FHID) {
    float v = part[0][tid] + part[1][tid] + part[2][tid] + part[3][tid] + b1[tid];
    hrow[tid] = v > 0.f ? v : 0.f;
  }
  __syncthreads();
  {
    int p = tid >> 7, j = tid & (FOUT - 1);
    float a2 = 0.f;
    const float* w2p = W2 + (size_t)(p * 32) * FOUT + j;
    const float* hp = hrow + p * 32;
    #pragma unroll 8
    for (int kk = 0; kk < 32; kk++) a2 += hp[kk] * w2p[(size_t)kk * FOUT];
    part2[p][j] = a2;
  }
  __syncthreads();
  if (tid < FOUT) {
    float sv = part2[0][tid] + part2[1][tid] + part2[2][tid] + part2[3][tid] +
               part2[4][tid] + part2[5][tid] + part2[6][tid] + part2[7][tid];
    HW2[((size_t)k * MS2 + s) * FOUT + tid] = sv;
  }
}

// K6: parallel resolve (r21) + accumulate + decoder.
__global__ __launch_bounds__(256) void k6_decode(const float* __restrict__ HW2,
                                                 const float* __restrict__ b2,
                                                 const int* __restrict__ cnt1,
                                                 const int* __restrict__ L1src,
                                                 const int* __restrict__ L1sel,
                                                 const int* __restrict__ idx,
                                                 const int* __restrict__ reg,
                                                 const int* __restrict__ bcnt,
                                                 const float* __restrict__ value,
                                                 const float* __restrict__ Wd,
                                                 const float* __restrict__ bd,
                                                 const float* __restrict__ Wp,
                                                 const float* __restrict__ bp,
                                                 float* __restrict__ out) {
  __shared__ float coefS[CAP1 + 2];
  __shared__ short slotS[CAP1 + 2];
  __shared__ short tselS[CAP1 + 2];
  __shared__ float hD[NH + 1];
  __shared__ float red[4];
  int k = blockIdx.x;
  int tid = threadIdx.x;
  const int* rk = reg + (size_t)k * NN;
  int n1 = min(cnt1[k], CAP1);
  int t0 = idx[2 * k], t1 = idx[2 * k + 1];
  int ts0 = rk[t0] - 1, ts1 = rk[t1] - 1;
  float dit0 = dinvf(bcnt[k * MS2 + ts0]);
  float dit1 = dinvf(bcnt[k * MS2 + ts1]);
  for (int i = tid; i < n1; i += 256) {
    int sn = L1src[k * CAP1 + i];
    int ts = L1sel[k * CAP1 + i];
    int ss = rk[sn] - 1;
    float dis = dinvf(bcnt[k * MS2 + ss]);
    coefS[i] = dis * (ts ? dit1 : dit0);
    slotS[i] = (short)ss;
    tselS[i] = (short)ts;
  }
  if (tid == 0) {
    coefS[n1] = dit0 * dit0; slotS[n1] = (short)ts0; tselS[n1] = 0;
    coefS[n1 + 1] = dit1 * dit1; slotS[n1 + 1] = (short)ts1; tselS[n1 + 1] = 1;
  }
  __syncthreads();
  {
    int tsel = tid >> 7, j = tid & 127;
    float acc = b2[j];
    int m = n1 + 2;
    for (int i = 0; i < m; i++) {
      if ((int)tselS[i] == tsel)
        acc += coefS[i] * HW2[((size_t)k * MS2 + (int)slotS[i]) * FOUT + j];
    }
    hD[tid] = acc;
    if (tid < 3) hD[2 * FOUT + tid] = value[k * 3 + tid];
  }
  __syncthreads();
  float a2 = bd[tid];
  for (int i = 0; i < NH; i++) a2 += hD[i] * Wd[(size_t)i * FHD + tid];
  float o = a2 > 0.f ? a2 : 0.f;
  float r = o * Wp[tid];
  for (int o2 = 32; o2 > 0; o2 >>= 1) r += __shfl_down(r, o2);
  if ((tid & 63) == 0) red[tid >> 6] = r;
  __syncthreads();
  if (tid == 0) {
    float ssum = red[0] + red[1] + red[2] + red[3] + bp[0];
    out[k] = 1.f / (1.f + expf(-ssum));
  }
}

extern "C" void kernel_launch(void* const* d_in, const int* in_sizes, int n_in,
                              void* d_out, int out_size, void* d_ws, size_t ws_size,
                              hipStream_t stream) {
  const float* x     = (const float*)d_in[0];
  const int*   ei    = (const int*)d_in[1];
  const float* value = (const float*)d_in[2];
  const int*   idx   = (const int*)d_in[3];
  const float* W1    = (const float*)d_in[4];
  const float* b1    = (const float*)d_in[5];
  const float* W2    = (const float*)d_in[6];
  const float* b2    = (const float*)d_in[7];
  const float* Wd    = (const float*)d_in[8];
  const float* bd    = (const float*)d_in[9];
  const float* Wp    = (const float*)d_in[10];
  const float* bp    = (const float*)d_in[11];
  float* out = (float*)d_out;

  char* ws = (char*)d_ws;
  size_t off = 0;
  auto alloc = [&](size_t bytes) -> void* {
    void* p = ws + off;
    off = (off + bytes + 255) & ~(size_t)255;
    return p;
  };
  // --- zeroed region (one kz_zero): reg, deg, bA, bB, bcnt, cnt1, mslots ---
  size_t zints = (size_t)(2 * KK * NN + 2 * KK * BMW + KK * MS2 + 2 * KK);
  int* reg   = (int*)alloc(zints * sizeof(int));
  int* deg   = reg + KK * NN;
  unsigned* bA = (unsigned*)(deg + KK * NN);
  unsigned* bB = bA + KK * BMW;
  int* bcnt  = (int*)(bB + KK * BMW);
  int* cnt1  = bcnt + KK * MS2;
  int* mslots = cnt1 + KK;
  size_t zbytes = zints * sizeof(int);
  // --- non-zeroed scratch ---
  int* L1src = (int*)alloc((size_t)KK * CAP1 * sizeof(int));
  int* L1sel = (int*)alloc((size_t)KK * CAP1 * sizeof(int));
  int* slotNode = (int*)alloc((size_t)KK * MS2 * sizeof(int));
  int* bucket = (int*)alloc((size_t)KK * MS2 * BCAP * sizeof(int));
  float* HW2 = (float*)alloc((size_t)KK * MS2 * FOUT * sizeof(float));
  (void)ws_size; (void)in_sizes; (void)n_in; (void)out_size;

  int n4 = (int)((zbytes + 15) / 16);
  dim3 escan((E4 + 255) / 256, KK);

  kz_zero<<<(n4 + 255) / 256, 256, 0, stream>>>((int4*)reg, n4);
  k12_scan_claim<<<escan, 256, 0, stream>>>(ei, idx, cnt1, L1src, L1sel,
                                            reg, slotNode, mslots, bA);
  k3_scanL2<<<escan, 256, 0, stream>>>(ei, reg, bA, bB, bcnt, bucket);
  k4_deg<<<escan, 256, 0, stream>>>(ei, bB, deg);
  k5_slotmlp<<<dim3(MS2, KK), 1024, 0, stream>>>(slotNode, mslots, bcnt, bucket, deg,
                                                 x, W1, b1, W2, HW2);
  k6_decode<<<dim3(KK), 256, 0, stream>>>(HW2, b2, cnt1, L1src, L1sel, idx, reg, bcnt,
                                          value, Wd, bd, Wp, bp, out);
}